// Round 1
// baseline (873.883 us; speedup 1.0000x reference)
//
#include <hip/hip_runtime.h>
#include <cstdint>
#include <cstddef>

// ---------------------------------------------------------------------------
// APPNP: h = MLP(x); h0 = h; 10x { h = 0.9 * A_w @ h + 0.1 * h0 }
// MLP in f16 MFMA (threshold is 2% of absmax; f16 rel err ~3e-4, 30x margin;
// propagation is linear in h0 so MLP error passes through unamplified).
// Propagation in fp32 via CSR gather (one wave per node, lane = feature).
// ---------------------------------------------------------------------------

#define N_NODES   65536
#define N_EDGES   1048576
#define IN_DIM    500
#define IN_PAD    512
#define HID_DIM   256
#define OUT_DIM   64
#define K_STEPS   10

typedef _Float16 half8 __attribute__((ext_vector_type(8)));
typedef float    f32x4 __attribute__((ext_vector_type(4)));

// ---- workspace layout (bytes) ---------------------------------------------
// xb region reused for ping-pong h buffers after GEMM1; h1 region reused for h0.
#define XB_OFF    0ULL                     // 65536*512*2  = 67108864 (f16 x, K-padded)
#define HA_OFF    0ULL                     // 16777216 (prop ping, reuses xb)
#define HB_OFF    33554432ULL              // 16777216 (prop pong, reuses xb)
#define H1_OFF    67108864ULL              // 65536*256*2 = 33554432 (f16)
#define H0_OFF    67108864ULL              // 16777216 fp32 (reuses h1 after GEMM2)
#define H2_OFF    100663296ULL             // 33554432 (f16)
#define W1T_OFF   134217728ULL             // 256*512*2 = 262144
#define W2T_OFF   134479872ULL             // 256*256*2 = 131072
#define W3T_OFF   134610944ULL             // 64*256*2  = 32768
#define ROWP_OFF  134643712ULL             // (N+1)*4
#define CNT_OFF   134906112ULL             // N*4
#define CUR_OFF   135168256ULL             // N*4
#define COLS_OFF  135430400ULL             // E*4
#define WSRT_OFF  139624704ULL             // E*4
// end ~ 143.8 MB

__device__ __forceinline__ void gload_lds16(const void* g, void* l) {
  // direct global->LDS DMA, 16B/lane; LDS dest = wave-uniform base + lane*16
  __builtin_amdgcn_global_load_lds(
      (const __attribute__((address_space(1))) void*)g,
      (__attribute__((address_space(3))) void*)l, 16, 0, 0);
}

// ---------------------------------------------------------------------------
// f16 MFMA GEMM: C[M,N] = A[M,K] @ B^T[N,K] + bias, optional relu.
// LDS layout: 16B chunks, chunk id = q*T + row (q = k/8 within the BK=64 slab)
// so both global_load_lds staging (lane-contiguous chunks) and ds_read_b128
// fragment reads (16 consecutive chunks per quarter-wave) are conflict-light.
// Wave w computes a 64x64 subtile: 4x4 grid of 16x16x32 MFMAs.
// ---------------------------------------------------------------------------
template <int TM, int TN, int WM, int WN, bool RELU, bool OUT_HALF>
__global__ __launch_bounds__(256)
void gemm_kernel(const _Float16* __restrict__ A, const _Float16* __restrict__ B,
                 const float* __restrict__ bias, void* __restrict__ Cout,
                 int M, int Nn, int K) {
  static_assert((TM * 8) % 256 == 0 && (TN * 8) % 256 == 0, "tile");
  __shared__ uint4 As[TM * 8];
  __shared__ uint4 Bs[TN * 8];
  const int t    = threadIdx.x;
  const int lane = t & 63;
  const int wave = t >> 6;
  const int wm   = wave / WN;
  const int wn   = wave % WN;
  const int row0 = blockIdx.x * TM;
  const int col0 = blockIdx.y * TN;
  const int l15  = lane & 15;
  const int lq   = lane >> 4;

  f32x4 acc[4][4];
#pragma unroll
  for (int i = 0; i < 4; ++i)
#pragma unroll
    for (int j = 0; j < 4; ++j) acc[i][j] = (f32x4){0.f, 0.f, 0.f, 0.f};

  for (int k0 = 0; k0 < K; k0 += 64) {
#pragma unroll
    for (int i = 0; i < (TM * 8) / 256; ++i) {
      const int c = i * 256 + wave * 64 + lane;
      const int q = c / TM;
      const int r = c % TM;
      gload_lds16(A + (size_t)(row0 + r) * K + (k0 + q * 8),
                  As + i * 256 + wave * 64);
    }
#pragma unroll
    for (int i = 0; i < (TN * 8) / 256; ++i) {
      const int c = i * 256 + wave * 64 + lane;
      const int q = c / TN;
      const int r = c % TN;
      gload_lds16(B + (size_t)(col0 + r) * K + (k0 + q * 8),
                  Bs + i * 256 + wave * 64);
    }
    __syncthreads();
#pragma unroll
    for (int kk = 0; kk < 2; ++kk) {
      const int qa = kk * 4 + lq;
      half8 af[4], bfr[4];
#pragma unroll
      for (int mt = 0; mt < 4; ++mt)
        af[mt] = *((const half8*)(As + (qa * TM + wm * 64 + mt * 16 + l15)));
#pragma unroll
      for (int nt = 0; nt < 4; ++nt)
        bfr[nt] = *((const half8*)(Bs + (qa * TN + wn * 64 + nt * 16 + l15)));
#pragma unroll
      for (int mt = 0; mt < 4; ++mt)
#pragma unroll
        for (int nt = 0; nt < 4; ++nt)
          acc[mt][nt] = __builtin_amdgcn_mfma_f32_16x16x32_f16(
              af[mt], bfr[nt], acc[mt][nt], 0, 0, 0);
    }
    __syncthreads();
  }

  // epilogue: C/D layout col = lane&15, row = (lane>>4)*4 + reg
#pragma unroll
  for (int mt = 0; mt < 4; ++mt) {
#pragma unroll
    for (int nt = 0; nt < 4; ++nt) {
      const int col = col0 + wn * 64 + nt * 16 + l15;
      const float bv = bias[col];
#pragma unroll
      for (int r = 0; r < 4; ++r) {
        const int row = row0 + wm * 64 + mt * 16 + lq * 4 + r;
        float v = acc[mt][nt][r] + bv;
        if (RELU) v = fmaxf(v, 0.f);
        if (OUT_HALF)
          ((_Float16*)Cout)[(size_t)row * Nn + col] = (_Float16)v;
        else
          ((float*)Cout)[(size_t)row * Nn + col] = v;
      }
    }
  }
}

// ---- cast x (fp32 MxK) -> f16 Mx512, zero-padded ---------------------------
__global__ void cast_x_kernel(const float* __restrict__ x,
                              _Float16* __restrict__ xb) {
  const int c = blockIdx.x * blockDim.x + threadIdx.x;  // one 8-col chunk
  if (c >= N_NODES * (IN_PAD / 8)) return;
  const int row = c >> 6;
  const int c8  = (c & 63) << 3;
  half8 o;
  if (c8 + 8 <= IN_DIM) {
    const float4* p = (const float4*)(x + (size_t)row * IN_DIM + c8);
    const float4 a = p[0], b = p[1];
    o[0] = (_Float16)a.x; o[1] = (_Float16)a.y;
    o[2] = (_Float16)a.z; o[3] = (_Float16)a.w;
    o[4] = (_Float16)b.x; o[5] = (_Float16)b.y;
    o[6] = (_Float16)b.z; o[7] = (_Float16)b.w;
  } else {
#pragma unroll
    for (int j = 0; j < 8; ++j) {
      const float v = (c8 + j < IN_DIM) ? x[(size_t)row * IN_DIM + c8 + j] : 0.f;
      o[j] = (_Float16)v;
    }
  }
  *(half8*)(xb + (size_t)c * 8) = o;
}

// ---- cast + transpose weight: W[K,N] fp32 -> Wt[N,Kpad] f16, zero-padded ---
__global__ void cast_w_kernel(const float* __restrict__ W,
                              _Float16* __restrict__ Wt, int K, int Kpad,
                              int Nn) {
  const int idx = blockIdx.x * blockDim.x + threadIdx.x;
  if (idx >= Nn * Kpad) return;
  const int n = idx / Kpad;
  const int k = idx % Kpad;
  const float v = (k < K) ? W[(size_t)k * Nn + n] : 0.f;
  Wt[idx] = (_Float16)v;
}

// ---- CSR build -------------------------------------------------------------
__global__ void hist_kernel(const int* __restrict__ row, int* __restrict__ cnt,
                            int E) {
  const int e = blockIdx.x * blockDim.x + threadIdx.x;
  if (e < E) atomicAdd(&cnt[row[e]], 1);
}

__global__ void scan_kernel(const int* __restrict__ counts,
                            int* __restrict__ rowptr,
                            int* __restrict__ cursor) {
  __shared__ int part[1024];
  const int t = threadIdx.x;
  const int base = t * 64;
  int s = 0;
  for (int i = 0; i < 64; ++i) s += counts[base + i];
  part[t] = s;
  __syncthreads();
  for (int off = 1; off < 1024; off <<= 1) {
    const int v = (t >= off) ? part[t - off] : 0;
    __syncthreads();
    part[t] += v;
    __syncthreads();
  }
  int run = (t == 0) ? 0 : part[t - 1];
  for (int i = 0; i < 64; ++i) {
    rowptr[base + i] = run;
    cursor[base + i] = run;
    run += counts[base + i];
  }
  if (t == 1023) rowptr[N_NODES] = run;
}

__global__ void scatter_kernel(const int* __restrict__ row,
                               const int* __restrict__ col,
                               const float* __restrict__ w,
                               int* __restrict__ cursor,
                               int* __restrict__ cols_s,
                               float* __restrict__ w_s, int E) {
  const int e = blockIdx.x * blockDim.x + threadIdx.x;
  if (e < E) {
    const int p = atomicAdd(&cursor[row[e]], 1);
    cols_s[p] = col[e];
    w_s[p] = w[e];
  }
}

// ---- propagation step: one wave per node, lane = feature -------------------
__global__ __launch_bounds__(256)
void prop_step(const float* __restrict__ hin, const float* __restrict__ h0,
               float* __restrict__ hout, const int* __restrict__ rowptr,
               const int* __restrict__ cols, const float* __restrict__ wv) {
  const int node = blockIdx.x * 4 + (threadIdx.x >> 6);
  const int lane = threadIdx.x & 63;
  const int beg = rowptr[node];
  const int end = rowptr[node + 1];
  float acc = 0.f;
  for (int e0 = beg; e0 < end; e0 += 64) {
    const int n = min(64, end - e0);
    int c = 0;
    float w = 0.f;
    if (lane < n) {
      c = cols[e0 + lane];
      w = wv[e0 + lane];
    }
    int j = 0;
    for (; j + 4 <= n; j += 4) {  // 4 loads in flight for L3 latency hiding
      const int c0 = __shfl(c, j), c1 = __shfl(c, j + 1);
      const int c2 = __shfl(c, j + 2), c3 = __shfl(c, j + 3);
      const float w0 = __shfl(w, j), w1 = __shfl(w, j + 1);
      const float w2 = __shfl(w, j + 2), w3 = __shfl(w, j + 3);
      const float v0 = hin[(size_t)c0 * 64 + lane];
      const float v1 = hin[(size_t)c1 * 64 + lane];
      const float v2 = hin[(size_t)c2 * 64 + lane];
      const float v3 = hin[(size_t)c3 * 64 + lane];
      acc += w0 * v0;
      acc += w1 * v1;
      acc += w2 * v2;
      acc += w3 * v3;
    }
    for (; j < n; ++j) {
      const int cj = __shfl(c, j);
      const float wj = __shfl(w, j);
      acc += wj * hin[(size_t)cj * 64 + lane];
    }
  }
  const size_t o = (size_t)node * 64 + lane;
  hout[o] = 0.9f * acc + 0.1f * h0[o];
}

// ---------------------------------------------------------------------------
extern "C" void kernel_launch(void* const* d_in, const int* in_sizes, int n_in,
                              void* d_out, int out_size, void* d_ws,
                              size_t ws_size, hipStream_t stream) {
  const float* x  = (const float*)d_in[0];
  const float* W1 = (const float*)d_in[1];
  const float* b1 = (const float*)d_in[2];
  const float* W2 = (const float*)d_in[3];
  const float* b2 = (const float*)d_in[4];
  const float* W3 = (const float*)d_in[5];
  const float* b3 = (const float*)d_in[6];
  const float* ew = (const float*)d_in[7];
  const int* erow = (const int*)d_in[8];
  const int* ecol = (const int*)d_in[9];

  char* ws = (char*)d_ws;
  _Float16* xb  = (_Float16*)(ws + XB_OFF);
  _Float16* h1  = (_Float16*)(ws + H1_OFF);
  _Float16* h2  = (_Float16*)(ws + H2_OFF);
  _Float16* w1t = (_Float16*)(ws + W1T_OFF);
  _Float16* w2t = (_Float16*)(ws + W2T_OFF);
  _Float16* w3t = (_Float16*)(ws + W3T_OFF);
  float* h0     = (float*)(ws + H0_OFF);
  float* hA     = (float*)(ws + HA_OFF);
  float* hB     = (float*)(ws + HB_OFF);
  int* rowp     = (int*)(ws + ROWP_OFF);
  int* cnt      = (int*)(ws + CNT_OFF);
  int* cur      = (int*)(ws + CUR_OFF);
  int* colss    = (int*)(ws + COLS_OFF);
  float* wsrt   = (float*)(ws + WSRT_OFF);
  float* outp   = (float*)d_out;

  // --- CSR build (independent of MLP; overlaps in stream order anyway) -----
  hipMemsetAsync(cnt, 0, N_NODES * sizeof(int), stream);
  hist_kernel<<<N_EDGES / 256, 256, 0, stream>>>(erow, cnt, N_EDGES);
  scan_kernel<<<1, 1024, 0, stream>>>(cnt, rowp, cur);
  scatter_kernel<<<N_EDGES / 256, 256, 0, stream>>>(erow, ecol, ew, cur, colss,
                                                    wsrt, N_EDGES);

  // --- MLP ------------------------------------------------------------------
  cast_x_kernel<<<(N_NODES * (IN_PAD / 8)) / 256, 256, 0, stream>>>(x, xb);
  cast_w_kernel<<<(HID_DIM * IN_PAD) / 256, 256, 0, stream>>>(W1, w1t, IN_DIM,
                                                              IN_PAD, HID_DIM);
  cast_w_kernel<<<(HID_DIM * HID_DIM) / 256, 256, 0, stream>>>(
      W2, w2t, HID_DIM, HID_DIM, HID_DIM);
  cast_w_kernel<<<(OUT_DIM * HID_DIM) / 256, 256, 0, stream>>>(
      W3, w3t, HID_DIM, HID_DIM, OUT_DIM);

  gemm_kernel<128, 128, 2, 2, true, true>
      <<<dim3(N_NODES / 128, HID_DIM / 128), 256, 0, stream>>>(
          xb, w1t, b1, h1, N_NODES, HID_DIM, IN_PAD);
  gemm_kernel<128, 128, 2, 2, true, true>
      <<<dim3(N_NODES / 128, HID_DIM / 128), 256, 0, stream>>>(
          h1, w2t, b2, h2, N_NODES, HID_DIM, HID_DIM);
  gemm_kernel<256, 64, 4, 1, false, false>
      <<<dim3(N_NODES / 256, 1), 256, 0, stream>>>(h2, w3t, b3, h0, N_NODES,
                                                   OUT_DIM, HID_DIM);

  // --- K=10 propagation -----------------------------------------------------
  for (int s = 0; s < K_STEPS; ++s) {
    const float* hin = (s == 0) ? h0 : ((s - 1) & 1 ? hB : hA);
    float* hout = (s == K_STEPS - 1) ? outp : ((s & 1) ? hB : hA);
    prop_step<<<N_NODES / 4, 256, 0, stream>>>(hin, h0, hout, rowp, colss,
                                               wsrt);
  }
}

// Round 2
// 864.386 us; speedup vs baseline: 1.0110x; 1.0110x over previous
//
#include <hip/hip_runtime.h>
#include <cstdint>
#include <cstddef>

// ---------------------------------------------------------------------------
// APPNP: h = MLP(x); h0 = h; 10x { h = 0.9 * A_w @ h + 0.1 * h0 }
// MLP in f16 MFMA (passed R1 with 3x absmax margin).
// Propagation fp32, CSR gather, one wave per node, lane = feature.
// R2: edge metadata via wave-uniform SCALAR loads (int2-packed), no shfl.
// ---------------------------------------------------------------------------

#define N_NODES   65536
#define N_EDGES   1048576
#define IN_DIM    500
#define IN_PAD    512
#define HID_DIM   256
#define OUT_DIM   64
#define K_STEPS   10

typedef _Float16 half8 __attribute__((ext_vector_type(8)));
typedef float    f32x4 __attribute__((ext_vector_type(4)));

// ---- workspace layout (bytes) ---------------------------------------------
#define XB_OFF    0ULL                     // 65536*512*2  = 67108864 (f16 x)
#define HA_OFF    0ULL                     // 16777216 (prop ping, reuses xb)
#define HB_OFF    33554432ULL              // 16777216 (prop pong, reuses xb)
#define H1_OFF    67108864ULL              // 33554432 (f16)
#define H0_OFF    67108864ULL              // 16777216 fp32 (reuses h1)
#define H2_OFF    100663296ULL             // 33554432 (f16)
#define W1T_OFF   134217728ULL             // 262144
#define W2T_OFF   134479872ULL             // 131072
#define W3T_OFF   134610944ULL             // 32768
#define ROWP_OFF  134643712ULL             // (N+1)*4
#define CNT_OFF   134906112ULL             // N*4
#define CUR_OFF   135168256ULL             // N*4
#define EDG_OFF   135430400ULL             // E*8 (int2: col, w-bits)
// end 143819008 (~137 MiB)

__device__ __forceinline__ void gload_lds16(const void* g, void* l) {
  __builtin_amdgcn_global_load_lds(
      (const __attribute__((address_space(1))) void*)g,
      (__attribute__((address_space(3))) void*)l, 16, 0, 0);
}

// ---------------------------------------------------------------------------
// f16 MFMA GEMM (unchanged from R1 — correct, minor cost)
// ---------------------------------------------------------------------------
template <int TM, int TN, int WM, int WN, bool RELU, bool OUT_HALF>
__global__ __launch_bounds__(256)
void gemm_kernel(const _Float16* __restrict__ A, const _Float16* __restrict__ B,
                 const float* __restrict__ bias, void* __restrict__ Cout,
                 int M, int Nn, int K) {
  static_assert((TM * 8) % 256 == 0 && (TN * 8) % 256 == 0, "tile");
  __shared__ uint4 As[TM * 8];
  __shared__ uint4 Bs[TN * 8];
  const int t    = threadIdx.x;
  const int lane = t & 63;
  const int wave = t >> 6;
  const int wm   = wave / WN;
  const int wn   = wave % WN;
  const int row0 = blockIdx.x * TM;
  const int col0 = blockIdx.y * TN;
  const int l15  = lane & 15;
  const int lq   = lane >> 4;

  f32x4 acc[4][4];
#pragma unroll
  for (int i = 0; i < 4; ++i)
#pragma unroll
    for (int j = 0; j < 4; ++j) acc[i][j] = (f32x4){0.f, 0.f, 0.f, 0.f};

  for (int k0 = 0; k0 < K; k0 += 64) {
#pragma unroll
    for (int i = 0; i < (TM * 8) / 256; ++i) {
      const int c = i * 256 + wave * 64 + lane;
      const int q = c / TM;
      const int r = c % TM;
      gload_lds16(A + (size_t)(row0 + r) * K + (k0 + q * 8),
                  As + i * 256 + wave * 64);
    }
#pragma unroll
    for (int i = 0; i < (TN * 8) / 256; ++i) {
      const int c = i * 256 + wave * 64 + lane;
      const int q = c / TN;
      const int r = c % TN;
      gload_lds16(B + (size_t)(col0 + r) * K + (k0 + q * 8),
                  Bs + i * 256 + wave * 64);
    }
    __syncthreads();
#pragma unroll
    for (int kk = 0; kk < 2; ++kk) {
      const int qa = kk * 4 + lq;
      half8 af[4], bfr[4];
#pragma unroll
      for (int mt = 0; mt < 4; ++mt)
        af[mt] = *((const half8*)(As + (qa * TM + wm * 64 + mt * 16 + l15)));
#pragma unroll
      for (int nt = 0; nt < 4; ++nt)
        bfr[nt] = *((const half8*)(Bs + (qa * TN + wn * 64 + nt * 16 + l15)));
#pragma unroll
      for (int mt = 0; mt < 4; ++mt)
#pragma unroll
        for (int nt = 0; nt < 4; ++nt)
          acc[mt][nt] = __builtin_amdgcn_mfma_f32_16x16x32_f16(
              af[mt], bfr[nt], acc[mt][nt], 0, 0, 0);
    }
    __syncthreads();
  }

#pragma unroll
  for (int mt = 0; mt < 4; ++mt) {
#pragma unroll
    for (int nt = 0; nt < 4; ++nt) {
      const int col = col0 + wn * 64 + nt * 16 + l15;
      const float bv = bias[col];
#pragma unroll
      for (int r = 0; r < 4; ++r) {
        const int row = row0 + wm * 64 + mt * 16 + lq * 4 + r;
        float v = acc[mt][nt][r] + bv;
        if (RELU) v = fmaxf(v, 0.f);
        if (OUT_HALF)
          ((_Float16*)Cout)[(size_t)row * Nn + col] = (_Float16)v;
        else
          ((float*)Cout)[(size_t)row * Nn + col] = v;
      }
    }
  }
}

// ---- cast x (fp32 MxK) -> f16 Mx512, zero-padded ---------------------------
__global__ void cast_x_kernel(const float* __restrict__ x,
                              _Float16* __restrict__ xb) {
  const int c = blockIdx.x * blockDim.x + threadIdx.x;
  if (c >= N_NODES * (IN_PAD / 8)) return;
  const int row = c >> 6;
  const int c8  = (c & 63) << 3;
  half8 o;
  if (c8 + 8 <= IN_DIM) {
    const float4* p = (const float4*)(x + (size_t)row * IN_DIM + c8);
    const float4 a = p[0], b = p[1];
    o[0] = (_Float16)a.x; o[1] = (_Float16)a.y;
    o[2] = (_Float16)a.z; o[3] = (_Float16)a.w;
    o[4] = (_Float16)b.x; o[5] = (_Float16)b.y;
    o[6] = (_Float16)b.z; o[7] = (_Float16)b.w;
  } else {
#pragma unroll
    for (int j = 0; j < 8; ++j) {
      const float v = (c8 + j < IN_DIM) ? x[(size_t)row * IN_DIM + c8 + j] : 0.f;
      o[j] = (_Float16)v;
    }
  }
  *(half8*)(xb + (size_t)c * 8) = o;
}

// ---- cast + transpose weight: W[K,N] fp32 -> Wt[N,Kpad] f16 ----------------
__global__ void cast_w_kernel(const float* __restrict__ W,
                              _Float16* __restrict__ Wt, int K, int Kpad,
                              int Nn) {
  const int idx = blockIdx.x * blockDim.x + threadIdx.x;
  if (idx >= Nn * Kpad) return;
  const int n = idx / Kpad;
  const int k = idx % Kpad;
  const float v = (k < K) ? W[(size_t)k * Nn + n] : 0.f;
  Wt[idx] = (_Float16)v;
}

// ---- CSR build -------------------------------------------------------------
__global__ void hist_kernel(const int* __restrict__ row, int* __restrict__ cnt,
                            int E) {
  const int e = blockIdx.x * blockDim.x + threadIdx.x;
  if (e < E) atomicAdd(&cnt[row[e]], 1);
}

__global__ void scan_kernel(const int4* __restrict__ counts4,
                            int* __restrict__ rowptr,
                            int* __restrict__ cursor) {
  __shared__ int part[1024];
  const int t = threadIdx.x;
  const int base = t * 16;  // int4 units; 64 ints per thread
  int4 c[16];
  int s = 0;
#pragma unroll
  for (int i = 0; i < 16; ++i) {
    c[i] = counts4[base + i];
    s += c[i].x + c[i].y + c[i].z + c[i].w;
  }
  part[t] = s;
  __syncthreads();
  for (int off = 1; off < 1024; off <<= 1) {
    const int v = (t >= off) ? part[t - off] : 0;
    __syncthreads();
    part[t] += v;
    __syncthreads();
  }
  int run = (t == 0) ? 0 : part[t - 1];
#pragma unroll
  for (int i = 0; i < 16; ++i) {
    int4 r;
    r.x = run; run += c[i].x;
    r.y = run; run += c[i].y;
    r.z = run; run += c[i].z;
    r.w = run; run += c[i].w;
    ((int4*)rowptr)[base + i] = r;
    ((int4*)cursor)[base + i] = r;
  }
  if (t == 1023) rowptr[N_NODES] = run;
}

__global__ void scatter_kernel(const int* __restrict__ row,
                               const int* __restrict__ col,
                               const float* __restrict__ w,
                               int* __restrict__ cursor,
                               int2* __restrict__ edges, int E) {
  const int e = blockIdx.x * blockDim.x + threadIdx.x;
  if (e < E) {
    const int p = atomicAdd(&cursor[row[e]], 1);
    edges[p] = make_int2(col[e], __float_as_int(w[e]));
  }
}

// ---- propagation: one wave per node, lane = feature ------------------------
// Edge metadata is wave-uniform -> force SGPR residency; the gather is the
// only per-lane memory op. 8 gathers in flight per wave.
__global__ __launch_bounds__(256)
void prop_step(const float* __restrict__ hin, const float* __restrict__ h0,
               float* __restrict__ hout, const int* __restrict__ rowptr,
               const int2* __restrict__ edges) {
  const int node =
      __builtin_amdgcn_readfirstlane((blockIdx.x << 2) + (threadIdx.x >> 6));
  const int lane = threadIdx.x & 63;
  const int beg = __builtin_amdgcn_readfirstlane(rowptr[node]);
  const int end = __builtin_amdgcn_readfirstlane(rowptr[node + 1]);

  float a0 = 0.f, a1 = 0.f, a2 = 0.f, a3 = 0.f;
  int e = beg;
  for (; e + 8 <= end; e += 8) {
    int   c0 = __builtin_amdgcn_readfirstlane(edges[e + 0].x);
    float w0 = __uint_as_float(__builtin_amdgcn_readfirstlane((unsigned)edges[e + 0].y));
    int   c1 = __builtin_amdgcn_readfirstlane(edges[e + 1].x);
    float w1 = __uint_as_float(__builtin_amdgcn_readfirstlane((unsigned)edges[e + 1].y));
    int   c2 = __builtin_amdgcn_readfirstlane(edges[e + 2].x);
    float w2 = __uint_as_float(__builtin_amdgcn_readfirstlane((unsigned)edges[e + 2].y));
    int   c3 = __builtin_amdgcn_readfirstlane(edges[e + 3].x);
    float w3 = __uint_as_float(__builtin_amdgcn_readfirstlane((unsigned)edges[e + 3].y));
    int   c4 = __builtin_amdgcn_readfirstlane(edges[e + 4].x);
    float w4 = __uint_as_float(__builtin_amdgcn_readfirstlane((unsigned)edges[e + 4].y));
    int   c5 = __builtin_amdgcn_readfirstlane(edges[e + 5].x);
    float w5 = __uint_as_float(__builtin_amdgcn_readfirstlane((unsigned)edges[e + 5].y));
    int   c6 = __builtin_amdgcn_readfirstlane(edges[e + 6].x);
    float w6 = __uint_as_float(__builtin_amdgcn_readfirstlane((unsigned)edges[e + 6].y));
    int   c7 = __builtin_amdgcn_readfirstlane(edges[e + 7].x);
    float w7 = __uint_as_float(__builtin_amdgcn_readfirstlane((unsigned)edges[e + 7].y));
    const float v0 = hin[((size_t)c0 << 6) | lane];
    const float v1 = hin[((size_t)c1 << 6) | lane];
    const float v2 = hin[((size_t)c2 << 6) | lane];
    const float v3 = hin[((size_t)c3 << 6) | lane];
    const float v4 = hin[((size_t)c4 << 6) | lane];
    const float v5 = hin[((size_t)c5 << 6) | lane];
    const float v6 = hin[((size_t)c6 << 6) | lane];
    const float v7 = hin[((size_t)c7 << 6) | lane];
    a0 = fmaf(w0, v0, a0);
    a1 = fmaf(w1, v1, a1);
    a2 = fmaf(w2, v2, a2);
    a3 = fmaf(w3, v3, a3);
    a0 = fmaf(w4, v4, a0);
    a1 = fmaf(w5, v5, a1);
    a2 = fmaf(w6, v6, a2);
    a3 = fmaf(w7, v7, a3);
  }
  for (; e < end; ++e) {
    const int   c = __builtin_amdgcn_readfirstlane(edges[e].x);
    const float w = __uint_as_float(__builtin_amdgcn_readfirstlane((unsigned)edges[e].y));
    a0 = fmaf(w, hin[((size_t)c << 6) | lane], a0);
  }
  const float acc = (a0 + a1) + (a2 + a3);
  const size_t o = ((size_t)node << 6) | lane;
  hout[o] = 0.9f * acc + 0.1f * h0[o];
}

// ---------------------------------------------------------------------------
extern "C" void kernel_launch(void* const* d_in, const int* in_sizes, int n_in,
                              void* d_out, int out_size, void* d_ws,
                              size_t ws_size, hipStream_t stream) {
  const float* x  = (const float*)d_in[0];
  const float* W1 = (const float*)d_in[1];
  const float* b1 = (const float*)d_in[2];
  const float* W2 = (const float*)d_in[3];
  const float* b2 = (const float*)d_in[4];
  const float* W3 = (const float*)d_in[5];
  const float* b3 = (const float*)d_in[6];
  const float* ew = (const float*)d_in[7];
  const int* erow = (const int*)d_in[8];
  const int* ecol = (const int*)d_in[9];

  char* ws = (char*)d_ws;
  _Float16* xb  = (_Float16*)(ws + XB_OFF);
  _Float16* h1  = (_Float16*)(ws + H1_OFF);
  _Float16* h2  = (_Float16*)(ws + H2_OFF);
  _Float16* w1t = (_Float16*)(ws + W1T_OFF);
  _Float16* w2t = (_Float16*)(ws + W2T_OFF);
  _Float16* w3t = (_Float16*)(ws + W3T_OFF);
  float* h0     = (float*)(ws + H0_OFF);
  float* hA     = (float*)(ws + HA_OFF);
  float* hB     = (float*)(ws + HB_OFF);
  int* rowp     = (int*)(ws + ROWP_OFF);
  int* cnt      = (int*)(ws + CNT_OFF);
  int* cur      = (int*)(ws + CUR_OFF);
  int2* edges   = (int2*)(ws + EDG_OFF);
  float* outp   = (float*)d_out;

  // --- CSR build ------------------------------------------------------------
  hipMemsetAsync(cnt, 0, N_NODES * sizeof(int), stream);
  hist_kernel<<<N_EDGES / 256, 256, 0, stream>>>(erow, cnt, N_EDGES);
  scan_kernel<<<1, 1024, 0, stream>>>((const int4*)cnt, rowp, cur);
  scatter_kernel<<<N_EDGES / 256, 256, 0, stream>>>(erow, ecol, ew, cur, edges,
                                                    N_EDGES);

  // --- MLP ------------------------------------------------------------------
  cast_x_kernel<<<(N_NODES * (IN_PAD / 8)) / 256, 256, 0, stream>>>(x, xb);
  cast_w_kernel<<<(HID_DIM * IN_PAD) / 256, 256, 0, stream>>>(W1, w1t, IN_DIM,
                                                              IN_PAD, HID_DIM);
  cast_w_kernel<<<(HID_DIM * HID_DIM) / 256, 256, 0, stream>>>(
      W2, w2t, HID_DIM, HID_DIM, HID_DIM);
  cast_w_kernel<<<(OUT_DIM * HID_DIM) / 256, 256, 0, stream>>>(
      W3, w3t, HID_DIM, HID_DIM, OUT_DIM);

  gemm_kernel<128, 128, 2, 2, true, true>
      <<<dim3(N_NODES / 128, HID_DIM / 128), 256, 0, stream>>>(
          xb, w1t, b1, h1, N_NODES, HID_DIM, IN_PAD);
  gemm_kernel<128, 128, 2, 2, true, true>
      <<<dim3(N_NODES / 128, HID_DIM / 128), 256, 0, stream>>>(
          h1, w2t, b2, h2, N_NODES, HID_DIM, HID_DIM);
  gemm_kernel<256, 64, 4, 1, false, false>
      <<<dim3(N_NODES / 256, 1), 256, 0, stream>>>(h2, w3t, b3, h0, N_NODES,
                                                   OUT_DIM, HID_DIM);

  // --- K=10 propagation -----------------------------------------------------
  for (int s = 0; s < K_STEPS; ++s) {
    const float* hin = (s == 0) ? h0 : ((s - 1) & 1 ? hB : hA);
    float* hout = (s == K_STEPS - 1) ? outp : ((s & 1) ? hB : hA);
    prop_step<<<N_NODES / 4, 256, 0, stream>>>(hin, h0, hout, rowp, edges);
  }
}

// Round 3
// 798.212 us; speedup vs baseline: 1.0948x; 1.0829x over previous
//
#include <hip/hip_runtime.h>
#include <cstdint>
#include <cstddef>

// ---------------------------------------------------------------------------
// APPNP: h = MLP(x); h0 = h; 10x { h = 0.9 * A_w @ h + 0.1 * h0 }
// MLP in f16 MFMA. Propagation state in bf16 (full f32 exponent range —
// values reach 1.6e8, f16 would overflow), accumulate f32 in registers,
// one bf16 RNE rounding per step; final step writes f32 straight to d_out.
// Gather traffic: 1M edges x 128 B rows = 134 MB/step (was 268 MB fp32).
// ---------------------------------------------------------------------------

#define N_NODES   65536
#define N_EDGES   1048576
#define IN_DIM    500
#define IN_PAD    512
#define HID_DIM   256
#define OUT_DIM   64
#define K_STEPS   10

typedef _Float16 half8 __attribute__((ext_vector_type(8)));
typedef float    f32x4 __attribute__((ext_vector_type(4)));

// ---- workspace layout (bytes) ---------------------------------------------
#define XB_OFF    0ULL                     // 67108864 (f16 x, K-padded)
#define HA_OFF    0ULL                     // bf16 prop ping (8 MB, reuses xb)
#define HB_OFF    33554432ULL              // bf16 prop pong (8 MB)
#define H1_OFF    67108864ULL              // 33554432 (f16)
#define H0_OFF    67108864ULL              // bf16 h0 (8 MB, reuses h1)
#define H2_OFF    100663296ULL             // 33554432 (f16)
#define W1T_OFF   134217728ULL             // 262144
#define W2T_OFF   134479872ULL             // 131072
#define W3T_OFF   134610944ULL             // 32768
#define ROWP_OFF  134643712ULL             // (N+1)*4
#define CNT_OFF   134906112ULL             // N*4
#define CUR_OFF   135168256ULL             // N*4
#define EDG_OFF   135430400ULL             // E*8 (int2: col, w-bits f32)
// end 143819008 (~137 MiB)

__device__ __forceinline__ void gload_lds16(const void* g, void* l) {
  __builtin_amdgcn_global_load_lds(
      (const __attribute__((address_space(1))) void*)g,
      (__attribute__((address_space(3))) void*)l, 16, 0, 0);
}

__device__ __forceinline__ float bf2f(unsigned short u) {
  return __uint_as_float(((unsigned)u) << 16);
}
__device__ __forceinline__ unsigned short f2bf_rne(float f) {
  unsigned u = __float_as_uint(f);
  u += 0x7fffu + ((u >> 16) & 1u);
  return (unsigned short)(u >> 16);
}

// ---------------------------------------------------------------------------
// f16 MFMA GEMM. OMODE: 0 = f16 out, 1 = bf16 out (ushort), 2 = f32 out.
// ---------------------------------------------------------------------------
template <int TM, int TN, int WM, int WN, bool RELU, int OMODE>
__global__ __launch_bounds__(256)
void gemm_kernel(const _Float16* __restrict__ A, const _Float16* __restrict__ B,
                 const float* __restrict__ bias, void* __restrict__ Cout,
                 int M, int Nn, int K) {
  static_assert((TM * 8) % 256 == 0 && (TN * 8) % 256 == 0, "tile");
  __shared__ uint4 As[TM * 8];
  __shared__ uint4 Bs[TN * 8];
  const int t    = threadIdx.x;
  const int lane = t & 63;
  const int wave = t >> 6;
  const int wm   = wave / WN;
  const int wn   = wave % WN;
  const int row0 = blockIdx.x * TM;
  const int col0 = blockIdx.y * TN;
  const int l15  = lane & 15;
  const int lq   = lane >> 4;

  f32x4 acc[4][4];
#pragma unroll
  for (int i = 0; i < 4; ++i)
#pragma unroll
    for (int j = 0; j < 4; ++j) acc[i][j] = (f32x4){0.f, 0.f, 0.f, 0.f};

  for (int k0 = 0; k0 < K; k0 += 64) {
#pragma unroll
    for (int i = 0; i < (TM * 8) / 256; ++i) {
      const int c = i * 256 + wave * 64 + lane;
      const int q = c / TM;
      const int r = c % TM;
      gload_lds16(A + (size_t)(row0 + r) * K + (k0 + q * 8),
                  As + i * 256 + wave * 64);
    }
#pragma unroll
    for (int i = 0; i < (TN * 8) / 256; ++i) {
      const int c = i * 256 + wave * 64 + lane;
      const int q = c / TN;
      const int r = c % TN;
      gload_lds16(B + (size_t)(col0 + r) * K + (k0 + q * 8),
                  Bs + i * 256 + wave * 64);
    }
    __syncthreads();
#pragma unroll
    for (int kk = 0; kk < 2; ++kk) {
      const int qa = kk * 4 + lq;
      half8 af[4], bfr[4];
#pragma unroll
      for (int mt = 0; mt < 4; ++mt)
        af[mt] = *((const half8*)(As + (qa * TM + wm * 64 + mt * 16 + l15)));
#pragma unroll
      for (int nt = 0; nt < 4; ++nt)
        bfr[nt] = *((const half8*)(Bs + (qa * TN + wn * 64 + nt * 16 + l15)));
#pragma unroll
      for (int mt = 0; mt < 4; ++mt)
#pragma unroll
        for (int nt = 0; nt < 4; ++nt)
          acc[mt][nt] = __builtin_amdgcn_mfma_f32_16x16x32_f16(
              af[mt], bfr[nt], acc[mt][nt], 0, 0, 0);
    }
    __syncthreads();
  }

#pragma unroll
  for (int mt = 0; mt < 4; ++mt) {
#pragma unroll
    for (int nt = 0; nt < 4; ++nt) {
      const int col = col0 + wn * 64 + nt * 16 + l15;
      const float bv = bias[col];
#pragma unroll
      for (int r = 0; r < 4; ++r) {
        const int row = row0 + wm * 64 + mt * 16 + lq * 4 + r;
        float v = acc[mt][nt][r] + bv;
        if (RELU) v = fmaxf(v, 0.f);
        if (OMODE == 0)
          ((_Float16*)Cout)[(size_t)row * Nn + col] = (_Float16)v;
        else if (OMODE == 1)
          ((unsigned short*)Cout)[(size_t)row * Nn + col] = f2bf_rne(v);
        else
          ((float*)Cout)[(size_t)row * Nn + col] = v;
      }
    }
  }
}

// ---- cast x (fp32 MxK) -> f16 Mx512, zero-padded ---------------------------
__global__ void cast_x_kernel(const float* __restrict__ x,
                              _Float16* __restrict__ xb) {
  const int c = blockIdx.x * blockDim.x + threadIdx.x;
  if (c >= N_NODES * (IN_PAD / 8)) return;
  const int row = c >> 6;
  const int c8  = (c & 63) << 3;
  half8 o;
  if (c8 + 8 <= IN_DIM) {
    const float4* p = (const float4*)(x + (size_t)row * IN_DIM + c8);
    const float4 a = p[0], b = p[1];
    o[0] = (_Float16)a.x; o[1] = (_Float16)a.y;
    o[2] = (_Float16)a.z; o[3] = (_Float16)a.w;
    o[4] = (_Float16)b.x; o[5] = (_Float16)b.y;
    o[6] = (_Float16)b.z; o[7] = (_Float16)b.w;
  } else {
#pragma unroll
    for (int j = 0; j < 8; ++j) {
      const float v = (c8 + j < IN_DIM) ? x[(size_t)row * IN_DIM + c8 + j] : 0.f;
      o[j] = (_Float16)v;
    }
  }
  *(half8*)(xb + (size_t)c * 8) = o;
}

// ---- cast + transpose weight: W[K,N] fp32 -> Wt[N,Kpad] f16 ----------------
__global__ void cast_w_kernel(const float* __restrict__ W,
                              _Float16* __restrict__ Wt, int K, int Kpad,
                              int Nn) {
  const int idx = blockIdx.x * blockDim.x + threadIdx.x;
  if (idx >= Nn * Kpad) return;
  const int n = idx / Kpad;
  const int k = idx % Kpad;
  const float v = (k < K) ? W[(size_t)k * Nn + n] : 0.f;
  Wt[idx] = (_Float16)v;
}

// ---- CSR build -------------------------------------------------------------
__global__ void hist_kernel(const int* __restrict__ row, int* __restrict__ cnt,
                            int E) {
  const int e = blockIdx.x * blockDim.x + threadIdx.x;
  if (e < E) atomicAdd(&cnt[row[e]], 1);
}

__global__ void scan_kernel(const int4* __restrict__ counts4,
                            int* __restrict__ rowptr,
                            int* __restrict__ cursor) {
  __shared__ int part[1024];
  const int t = threadIdx.x;
  const int base = t * 16;  // int4 units; 64 ints per thread
  int4 c[16];
  int s = 0;
#pragma unroll
  for (int i = 0; i < 16; ++i) {
    c[i] = counts4[base + i];
    s += c[i].x + c[i].y + c[i].z + c[i].w;
  }
  part[t] = s;
  __syncthreads();
  for (int off = 1; off < 1024; off <<= 1) {
    const int v = (t >= off) ? part[t - off] : 0;
    __syncthreads();
    part[t] += v;
    __syncthreads();
  }
  int run = (t == 0) ? 0 : part[t - 1];
#pragma unroll
  for (int i = 0; i < 16; ++i) {
    int4 r;
    r.x = run; run += c[i].x;
    r.y = run; run += c[i].y;
    r.z = run; run += c[i].z;
    r.w = run; run += c[i].w;
    ((int4*)rowptr)[base + i] = r;
    ((int4*)cursor)[base + i] = r;
  }
  if (t == 1023) rowptr[N_NODES] = run;
}

__global__ void scatter_kernel(const int* __restrict__ row,
                               const int* __restrict__ col,
                               const float* __restrict__ w,
                               int* __restrict__ cursor,
                               int2* __restrict__ edges, int E) {
  const int e = blockIdx.x * blockDim.x + threadIdx.x;
  if (e < E) {
    const int p = atomicAdd(&cursor[row[e]], 1);
    edges[p] = make_int2(col[e], __float_as_int(w[e]));
  }
}

// ---- propagation: one wave per node, lane = feature, bf16 state ------------
template <bool OUT_F32>
__global__ __launch_bounds__(256)
void prop_step(const unsigned short* __restrict__ hin,
               const unsigned short* __restrict__ h0,
               void* __restrict__ hout, const int* __restrict__ rowptr,
               const int2* __restrict__ edges) {
  const int node =
      __builtin_amdgcn_readfirstlane((blockIdx.x << 2) + (threadIdx.x >> 6));
  const int lane = threadIdx.x & 63;
  const int beg = __builtin_amdgcn_readfirstlane(rowptr[node]);
  const int end = __builtin_amdgcn_readfirstlane(rowptr[node + 1]);

  float a0 = 0.f, a1 = 0.f, a2 = 0.f, a3 = 0.f;
  int e = beg;
  for (; e + 8 <= end; e += 8) {
    int   c0 = __builtin_amdgcn_readfirstlane(edges[e + 0].x);
    float w0 = __uint_as_float(__builtin_amdgcn_readfirstlane((unsigned)edges[e + 0].y));
    int   c1 = __builtin_amdgcn_readfirstlane(edges[e + 1].x);
    float w1 = __uint_as_float(__builtin_amdgcn_readfirstlane((unsigned)edges[e + 1].y));
    int   c2 = __builtin_amdgcn_readfirstlane(edges[e + 2].x);
    float w2 = __uint_as_float(__builtin_amdgcn_readfirstlane((unsigned)edges[e + 2].y));
    int   c3 = __builtin_amdgcn_readfirstlane(edges[e + 3].x);
    float w3 = __uint_as_float(__builtin_amdgcn_readfirstlane((unsigned)edges[e + 3].y));
    int   c4 = __builtin_amdgcn_readfirstlane(edges[e + 4].x);
    float w4 = __uint_as_float(__builtin_amdgcn_readfirstlane((unsigned)edges[e + 4].y));
    int   c5 = __builtin_amdgcn_readfirstlane(edges[e + 5].x);
    float w5 = __uint_as_float(__builtin_amdgcn_readfirstlane((unsigned)edges[e + 5].y));
    int   c6 = __builtin_amdgcn_readfirstlane(edges[e + 6].x);
    float w6 = __uint_as_float(__builtin_amdgcn_readfirstlane((unsigned)edges[e + 6].y));
    int   c7 = __builtin_amdgcn_readfirstlane(edges[e + 7].x);
    float w7 = __uint_as_float(__builtin_amdgcn_readfirstlane((unsigned)edges[e + 7].y));
    const float v0 = bf2f(hin[((size_t)c0 << 6) | lane]);
    const float v1 = bf2f(hin[((size_t)c1 << 6) | lane]);
    const float v2 = bf2f(hin[((size_t)c2 << 6) | lane]);
    const float v3 = bf2f(hin[((size_t)c3 << 6) | lane]);
    const float v4 = bf2f(hin[((size_t)c4 << 6) | lane]);
    const float v5 = bf2f(hin[((size_t)c5 << 6) | lane]);
    const float v6 = bf2f(hin[((size_t)c6 << 6) | lane]);
    const float v7 = bf2f(hin[((size_t)c7 << 6) | lane]);
    a0 = fmaf(w0, v0, a0);
    a1 = fmaf(w1, v1, a1);
    a2 = fmaf(w2, v2, a2);
    a3 = fmaf(w3, v3, a3);
    a0 = fmaf(w4, v4, a0);
    a1 = fmaf(w5, v5, a1);
    a2 = fmaf(w6, v6, a2);
    a3 = fmaf(w7, v7, a3);
  }
  for (; e < end; ++e) {
    const int   c = __builtin_amdgcn_readfirstlane(edges[e].x);
    const float w = __uint_as_float(__builtin_amdgcn_readfirstlane((unsigned)edges[e].y));
    a0 = fmaf(w, bf2f(hin[((size_t)c << 6) | lane]), a0);
  }
  const float acc = (a0 + a1) + (a2 + a3);
  const size_t o = ((size_t)node << 6) | lane;
  const float r = 0.9f * acc + 0.1f * bf2f(h0[o]);
  if (OUT_F32)
    ((float*)hout)[o] = r;
  else
    ((unsigned short*)hout)[o] = f2bf_rne(r);
}

// ---------------------------------------------------------------------------
extern "C" void kernel_launch(void* const* d_in, const int* in_sizes, int n_in,
                              void* d_out, int out_size, void* d_ws,
                              size_t ws_size, hipStream_t stream) {
  const float* x  = (const float*)d_in[0];
  const float* W1 = (const float*)d_in[1];
  const float* b1 = (const float*)d_in[2];
  const float* W2 = (const float*)d_in[3];
  const float* b2 = (const float*)d_in[4];
  const float* W3 = (const float*)d_in[5];
  const float* b3 = (const float*)d_in[6];
  const float* ew = (const float*)d_in[7];
  const int* erow = (const int*)d_in[8];
  const int* ecol = (const int*)d_in[9];

  char* ws = (char*)d_ws;
  _Float16* xb  = (_Float16*)(ws + XB_OFF);
  _Float16* h1  = (_Float16*)(ws + H1_OFF);
  _Float16* h2  = (_Float16*)(ws + H2_OFF);
  _Float16* w1t = (_Float16*)(ws + W1T_OFF);
  _Float16* w2t = (_Float16*)(ws + W2T_OFF);
  _Float16* w3t = (_Float16*)(ws + W3T_OFF);
  unsigned short* h0b = (unsigned short*)(ws + H0_OFF);
  unsigned short* hAb = (unsigned short*)(ws + HA_OFF);
  unsigned short* hBb = (unsigned short*)(ws + HB_OFF);
  int* rowp     = (int*)(ws + ROWP_OFF);
  int* cnt      = (int*)(ws + CNT_OFF);
  int* cur      = (int*)(ws + CUR_OFF);
  int2* edges   = (int2*)(ws + EDG_OFF);
  float* outp   = (float*)d_out;

  // --- CSR build ------------------------------------------------------------
  hipMemsetAsync(cnt, 0, N_NODES * sizeof(int), stream);
  hist_kernel<<<N_EDGES / 256, 256, 0, stream>>>(erow, cnt, N_EDGES);
  scan_kernel<<<1, 1024, 0, stream>>>((const int4*)cnt, rowp, cur);
  scatter_kernel<<<N_EDGES / 256, 256, 0, stream>>>(erow, ecol, ew, cur, edges,
                                                    N_EDGES);

  // --- MLP ------------------------------------------------------------------
  cast_x_kernel<<<(N_NODES * (IN_PAD / 8)) / 256, 256, 0, stream>>>(x, xb);
  cast_w_kernel<<<(HID_DIM * IN_PAD) / 256, 256, 0, stream>>>(W1, w1t, IN_DIM,
                                                              IN_PAD, HID_DIM);
  cast_w_kernel<<<(HID_DIM * HID_DIM) / 256, 256, 0, stream>>>(
      W2, w2t, HID_DIM, HID_DIM, HID_DIM);
  cast_w_kernel<<<(OUT_DIM * HID_DIM) / 256, 256, 0, stream>>>(
      W3, w3t, HID_DIM, HID_DIM, OUT_DIM);

  gemm_kernel<128, 128, 2, 2, true, 0>
      <<<dim3(N_NODES / 128, HID_DIM / 128), 256, 0, stream>>>(
          xb, w1t, b1, h1, N_NODES, HID_DIM, IN_PAD);
  gemm_kernel<128, 128, 2, 2, true, 0>
      <<<dim3(N_NODES / 128, HID_DIM / 128), 256, 0, stream>>>(
          h1, w2t, b2, h2, N_NODES, HID_DIM, HID_DIM);
  gemm_kernel<256, 64, 4, 1, false, 1>
      <<<dim3(N_NODES / 256, 1), 256, 0, stream>>>(h2, w3t, b3, h0b, N_NODES,
                                                   OUT_DIM, HID_DIM);

  // --- K=10 propagation (bf16 state; last step writes f32 to d_out) --------
  for (int s = 0; s < K_STEPS - 1; ++s) {
    const unsigned short* hin = (s == 0) ? h0b : ((s - 1) & 1 ? hBb : hAb);
    unsigned short* hout = (s & 1) ? hBb : hAb;
    prop_step<false><<<N_NODES / 4, 256, 0, stream>>>(hin, h0b, hout, rowp,
                                                      edges);
  }
  prop_step<true><<<N_NODES / 4, 256, 0, stream>>>(
      (K_STEPS - 2) & 1 ? hBb : hAb, h0b, outp, rowp, edges);
}

// Round 4
// 743.728 us; speedup vs baseline: 1.1750x; 1.0733x over previous
//
#include <hip/hip_runtime.h>
#include <cstdint>
#include <cstddef>

// ---------------------------------------------------------------------------
// APPNP: h = MLP(x); h0 = h; 10x { h = 0.9 * A_w @ h + 0.1 * h0 }
// MLP in f16 MFMA. Propagation state bf16, accumulate f32.
// R4: prop restructured for memory-level parallelism — each wave stages the
// CSR edge range of its 8 nodes into LDS (one coalesced burst), then issues
// gathers back-to-back (no global->global serial dependency per batch).
// ---------------------------------------------------------------------------

#define N_NODES   65536
#define N_EDGES   1048576
#define IN_DIM    500
#define IN_PAD    512
#define HID_DIM   256
#define OUT_DIM   64
#define K_STEPS   10

#define NPW   8      // nodes per wave in prop
#define CAPW  608    // per-wave LDS edge capacity (int2) -> 19456 B/block

typedef _Float16 half8 __attribute__((ext_vector_type(8)));
typedef float    f32x4 __attribute__((ext_vector_type(4)));

// ---- workspace layout (bytes) ---------------------------------------------
#define XB_OFF    0ULL                     // 67108864 (f16 x, K-padded)
#define HA_OFF    0ULL                     // bf16 prop ping (8 MB, reuses xb)
#define HB_OFF    33554432ULL              // bf16 prop pong (8 MB)
#define H1_OFF    67108864ULL              // 33554432 (f16)
#define H0_OFF    67108864ULL              // bf16 h0 (8 MB, reuses h1)
#define H2_OFF    100663296ULL             // 33554432 (f16)
#define W1T_OFF   134217728ULL             // 262144
#define W2T_OFF   134479872ULL             // 131072
#define W3T_OFF   134610944ULL             // 32768
#define ROWP_OFF  134643712ULL             // (N+1)*4
#define CNT_OFF   134906112ULL             // N*4
#define CUR_OFF   135168256ULL             // N*4
#define EDG_OFF   135430400ULL             // E*8 (int2: col, w-bits f32)
// end 143819008 (~137 MiB)

__device__ __forceinline__ void gload_lds16(const void* g, void* l) {
  __builtin_amdgcn_global_load_lds(
      (const __attribute__((address_space(1))) void*)g,
      (__attribute__((address_space(3))) void*)l, 16, 0, 0);
}

__device__ __forceinline__ float bf2f(unsigned short u) {
  return __uint_as_float(((unsigned)u) << 16);
}
__device__ __forceinline__ unsigned short f2bf_rne(float f) {
  unsigned u = __float_as_uint(f);
  u += 0x7fffu + ((u >> 16) & 1u);
  return (unsigned short)(u >> 16);
}

// ---------------------------------------------------------------------------
// f16 MFMA GEMM. OMODE: 0 = f16 out, 1 = bf16 out (ushort), 2 = f32 out.
// ---------------------------------------------------------------------------
template <int TM, int TN, int WM, int WN, bool RELU, int OMODE>
__global__ __launch_bounds__(256)
void gemm_kernel(const _Float16* __restrict__ A, const _Float16* __restrict__ B,
                 const float* __restrict__ bias, void* __restrict__ Cout,
                 int M, int Nn, int K) {
  static_assert((TM * 8) % 256 == 0 && (TN * 8) % 256 == 0, "tile");
  __shared__ uint4 As[TM * 8];
  __shared__ uint4 Bs[TN * 8];
  const int t    = threadIdx.x;
  const int lane = t & 63;
  const int wave = t >> 6;
  const int wm   = wave / WN;
  const int wn   = wave % WN;
  const int row0 = blockIdx.x * TM;
  const int col0 = blockIdx.y * TN;
  const int l15  = lane & 15;
  const int lq   = lane >> 4;

  f32x4 acc[4][4];
#pragma unroll
  for (int i = 0; i < 4; ++i)
#pragma unroll
    for (int j = 0; j < 4; ++j) acc[i][j] = (f32x4){0.f, 0.f, 0.f, 0.f};

  for (int k0 = 0; k0 < K; k0 += 64) {
#pragma unroll
    for (int i = 0; i < (TM * 8) / 256; ++i) {
      const int c = i * 256 + wave * 64 + lane;
      const int q = c / TM;
      const int r = c % TM;
      gload_lds16(A + (size_t)(row0 + r) * K + (k0 + q * 8),
                  As + i * 256 + wave * 64);
    }
#pragma unroll
    for (int i = 0; i < (TN * 8) / 256; ++i) {
      const int c = i * 256 + wave * 64 + lane;
      const int q = c / TN;
      const int r = c % TN;
      gload_lds16(B + (size_t)(col0 + r) * K + (k0 + q * 8),
                  Bs + i * 256 + wave * 64);
    }
    __syncthreads();
#pragma unroll
    for (int kk = 0; kk < 2; ++kk) {
      const int qa = kk * 4 + lq;
      half8 af[4], bfr[4];
#pragma unroll
      for (int mt = 0; mt < 4; ++mt)
        af[mt] = *((const half8*)(As + (qa * TM + wm * 64 + mt * 16 + l15)));
#pragma unroll
      for (int nt = 0; nt < 4; ++nt)
        bfr[nt] = *((const half8*)(Bs + (qa * TN + wn * 64 + nt * 16 + l15)));
#pragma unroll
      for (int mt = 0; mt < 4; ++mt)
#pragma unroll
        for (int nt = 0; nt < 4; ++nt)
          acc[mt][nt] = __builtin_amdgcn_mfma_f32_16x16x32_f16(
              af[mt], bfr[nt], acc[mt][nt], 0, 0, 0);
    }
    __syncthreads();
  }

#pragma unroll
  for (int mt = 0; mt < 4; ++mt) {
#pragma unroll
    for (int nt = 0; nt < 4; ++nt) {
      const int col = col0 + wn * 64 + nt * 16 + l15;
      const float bv = bias[col];
#pragma unroll
      for (int r = 0; r < 4; ++r) {
        const int row = row0 + wm * 64 + mt * 16 + lq * 4 + r;
        float v = acc[mt][nt][r] + bv;
        if (RELU) v = fmaxf(v, 0.f);
        if (OMODE == 0)
          ((_Float16*)Cout)[(size_t)row * Nn + col] = (_Float16)v;
        else if (OMODE == 1)
          ((unsigned short*)Cout)[(size_t)row * Nn + col] = f2bf_rne(v);
        else
          ((float*)Cout)[(size_t)row * Nn + col] = v;
      }
    }
  }
}

// ---- cast x (fp32 MxK) -> f16 Mx512, zero-padded ---------------------------
__global__ void cast_x_kernel(const float* __restrict__ x,
                              _Float16* __restrict__ xb) {
  const int c = blockIdx.x * blockDim.x + threadIdx.x;
  if (c >= N_NODES * (IN_PAD / 8)) return;
  const int row = c >> 6;
  const int c8  = (c & 63) << 3;
  half8 o;
  if (c8 + 8 <= IN_DIM) {
    const float4* p = (const float4*)(x + (size_t)row * IN_DIM + c8);
    const float4 a = p[0], b = p[1];
    o[0] = (_Float16)a.x; o[1] = (_Float16)a.y;
    o[2] = (_Float16)a.z; o[3] = (_Float16)a.w;
    o[4] = (_Float16)b.x; o[5] = (_Float16)b.y;
    o[6] = (_Float16)b.z; o[7] = (_Float16)b.w;
  } else {
#pragma unroll
    for (int j = 0; j < 8; ++j) {
      const float v = (c8 + j < IN_DIM) ? x[(size_t)row * IN_DIM + c8 + j] : 0.f;
      o[j] = (_Float16)v;
    }
  }
  *(half8*)(xb + (size_t)c * 8) = o;
}

// ---- cast + transpose weight: W[K,N] fp32 -> Wt[N,Kpad] f16 ----------------
__global__ void cast_w_kernel(const float* __restrict__ W,
                              _Float16* __restrict__ Wt, int K, int Kpad,
                              int Nn) {
  const int idx = blockIdx.x * blockDim.x + threadIdx.x;
  if (idx >= Nn * Kpad) return;
  const int n = idx / Kpad;
  const int k = idx % Kpad;
  const float v = (k < K) ? W[(size_t)k * Nn + n] : 0.f;
  Wt[idx] = (_Float16)v;
}

// ---- CSR build -------------------------------------------------------------
__global__ void hist_kernel(const int* __restrict__ row, int* __restrict__ cnt,
                            int E) {
  const int e = blockIdx.x * blockDim.x + threadIdx.x;
  if (e < E) atomicAdd(&cnt[row[e]], 1);
}

__global__ void scan_kernel(const int4* __restrict__ counts4,
                            int* __restrict__ rowptr,
                            int* __restrict__ cursor) {
  __shared__ int part[1024];
  const int t = threadIdx.x;
  const int base = t * 16;  // int4 units; 64 ints per thread
  int4 c[16];
  int s = 0;
#pragma unroll
  for (int i = 0; i < 16; ++i) {
    c[i] = counts4[base + i];
    s += c[i].x + c[i].y + c[i].z + c[i].w;
  }
  part[t] = s;
  __syncthreads();
  for (int off = 1; off < 1024; off <<= 1) {
    const int v = (t >= off) ? part[t - off] : 0;
    __syncthreads();
    part[t] += v;
    __syncthreads();
  }
  int run = (t == 0) ? 0 : part[t - 1];
#pragma unroll
  for (int i = 0; i < 16; ++i) {
    int4 r;
    r.x = run; run += c[i].x;
    r.y = run; run += c[i].y;
    r.z = run; run += c[i].z;
    r.w = run; run += c[i].w;
    ((int4*)rowptr)[base + i] = r;
    ((int4*)cursor)[base + i] = r;
  }
  if (t == 1023) rowptr[N_NODES] = run;
}

__global__ void scatter_kernel(const int* __restrict__ row,
                               const int* __restrict__ col,
                               const float* __restrict__ w,
                               int* __restrict__ cursor,
                               int2* __restrict__ edges, int E) {
  const int e = blockIdx.x * blockDim.x + threadIdx.x;
  if (e < E) {
    const int p = atomicAdd(&cursor[row[e]], 1);
    edges[p] = make_int2(col[e], __float_as_int(w[e]));
  }
}

// ---- propagation: wave handles NPW nodes; edges staged in LDS --------------
// The wave's whole CSR edge range is loaded with one coalesced burst into a
// private LDS slab; gathers then issue back-to-back with only ds_read (20cyc
// issue) between them -> outstanding-line count per CU rises ~10x.
template <bool OUT_F32>
__global__ __launch_bounds__(256)
void prop_step(const unsigned short* __restrict__ hin,
               const unsigned short* __restrict__ h0,
               void* __restrict__ hout, const int* __restrict__ rowptr,
               const int2* __restrict__ edges) {
  __shared__ int2 eb[4][CAPW];
  const int wave = threadIdx.x >> 6;
  const int lane = threadIdx.x & 63;
  const int node0 = (blockIdx.x * 4 + wave) * NPW;

  // lanes 0..NPW hold rowptr[node0 + lane]; others duplicate rowptr[node0+NPW]
  const int rp  = rowptr[node0 + min(lane, NPW)];
  const int beg = __shfl(rp, 0);
  const int nE  = __shfl(rp, NPW) - beg;
  const int rrel = rp - beg;
  int2* __restrict__ ebw = eb[wave];

  const bool fast = (nE <= CAPW);
  if (fast) {
    for (int i = lane; i < nE; i += 64) ebw[i] = edges[beg + i];
    __builtin_amdgcn_s_waitcnt(0);  // drain vm+lgkm: staging visible wave-wide
  }

  for (int i = 0; i < NPW; ++i) {
    const int nb = __shfl(rrel, i);
    const int ne = __shfl(rrel, i + 1);
    float a0 = 0.f, a1 = 0.f, a2 = 0.f, a3 = 0.f;
    if (fast) {
      int j = nb;
      for (; j + 4 <= ne; j += 4) {
        const int2 e0 = ebw[j + 0];
        const int2 e1 = ebw[j + 1];
        const int2 e2 = ebw[j + 2];
        const int2 e3 = ebw[j + 3];
        const float v0 = bf2f(hin[((size_t)e0.x << 6) | lane]);
        const float v1 = bf2f(hin[((size_t)e1.x << 6) | lane]);
        const float v2 = bf2f(hin[((size_t)e2.x << 6) | lane]);
        const float v3 = bf2f(hin[((size_t)e3.x << 6) | lane]);
        a0 = fmaf(__uint_as_float((unsigned)e0.y), v0, a0);
        a1 = fmaf(__uint_as_float((unsigned)e1.y), v1, a1);
        a2 = fmaf(__uint_as_float((unsigned)e2.y), v2, a2);
        a3 = fmaf(__uint_as_float((unsigned)e3.y), v3, a3);
      }
      for (; j < ne; ++j) {
        const int2 e = ebw[j];
        a0 = fmaf(__uint_as_float((unsigned)e.y),
                  bf2f(hin[((size_t)e.x << 6) | lane]), a0);
      }
    } else {  // degenerate degree distribution: direct-global path
      for (int j = nb; j < ne; ++j) {
        const int2 e = edges[beg + j];
        a0 = fmaf(__uint_as_float((unsigned)e.y),
                  bf2f(hin[((size_t)e.x << 6) | lane]), a0);
      }
    }
    const float acc = (a0 + a1) + (a2 + a3);
    const size_t o = ((size_t)(node0 + i) << 6) | lane;
    const float r = 0.9f * acc + 0.1f * bf2f(h0[o]);
    if (OUT_F32)
      ((float*)hout)[o] = r;
    else
      ((unsigned short*)hout)[o] = f2bf_rne(r);
  }
}

// ---------------------------------------------------------------------------
extern "C" void kernel_launch(void* const* d_in, const int* in_sizes, int n_in,
                              void* d_out, int out_size, void* d_ws,
                              size_t ws_size, hipStream_t stream) {
  const float* x  = (const float*)d_in[0];
  const float* W1 = (const float*)d_in[1];
  const float* b1 = (const float*)d_in[2];
  const float* W2 = (const float*)d_in[3];
  const float* b2 = (const float*)d_in[4];
  const float* W3 = (const float*)d_in[5];
  const float* b3 = (const float*)d_in[6];
  const float* ew = (const float*)d_in[7];
  const int* erow = (const int*)d_in[8];
  const int* ecol = (const int*)d_in[9];

  char* ws = (char*)d_ws;
  _Float16* xb  = (_Float16*)(ws + XB_OFF);
  _Float16* h1  = (_Float16*)(ws + H1_OFF);
  _Float16* h2  = (_Float16*)(ws + H2_OFF);
  _Float16* w1t = (_Float16*)(ws + W1T_OFF);
  _Float16* w2t = (_Float16*)(ws + W2T_OFF);
  _Float16* w3t = (_Float16*)(ws + W3T_OFF);
  unsigned short* h0b = (unsigned short*)(ws + H0_OFF);
  unsigned short* hAb = (unsigned short*)(ws + HA_OFF);
  unsigned short* hBb = (unsigned short*)(ws + HB_OFF);
  int* rowp     = (int*)(ws + ROWP_OFF);
  int* cnt      = (int*)(ws + CNT_OFF);
  int* cur      = (int*)(ws + CUR_OFF);
  int2* edges   = (int2*)(ws + EDG_OFF);
  float* outp   = (float*)d_out;

  // --- CSR build ------------------------------------------------------------
  hipMemsetAsync(cnt, 0, N_NODES * sizeof(int), stream);
  hist_kernel<<<N_EDGES / 256, 256, 0, stream>>>(erow, cnt, N_EDGES);
  scan_kernel<<<1, 1024, 0, stream>>>((const int4*)cnt, rowp, cur);
  scatter_kernel<<<N_EDGES / 256, 256, 0, stream>>>(erow, ecol, ew, cur, edges,
                                                    N_EDGES);

  // --- MLP ------------------------------------------------------------------
  cast_x_kernel<<<(N_NODES * (IN_PAD / 8)) / 256, 256, 0, stream>>>(x, xb);
  cast_w_kernel<<<(HID_DIM * IN_PAD) / 256, 256, 0, stream>>>(W1, w1t, IN_DIM,
                                                              IN_PAD, HID_DIM);
  cast_w_kernel<<<(HID_DIM * HID_DIM) / 256, 256, 0, stream>>>(
      W2, w2t, HID_DIM, HID_DIM, HID_DIM);
  cast_w_kernel<<<(OUT_DIM * HID_DIM) / 256, 256, 0, stream>>>(
      W3, w3t, HID_DIM, HID_DIM, OUT_DIM);

  gemm_kernel<128, 128, 2, 2, true, 0>
      <<<dim3(N_NODES / 128, HID_DIM / 128), 256, 0, stream>>>(
          xb, w1t, b1, h1, N_NODES, HID_DIM, IN_PAD);
  gemm_kernel<128, 128, 2, 2, true, 0>
      <<<dim3(N_NODES / 128, HID_DIM / 128), 256, 0, stream>>>(
          h1, w2t, b2, h2, N_NODES, HID_DIM, HID_DIM);
  gemm_kernel<256, 64, 4, 1, false, 1>
      <<<dim3(N_NODES / 256, 1), 256, 0, stream>>>(h2, w3t, b3, h0b, N_NODES,
                                                   OUT_DIM, HID_DIM);

  // --- K=10 propagation (bf16 state; last step writes f32 to d_out) --------
  for (int s = 0; s < K_STEPS - 1; ++s) {
    const unsigned short* hin = (s == 0) ? h0b : ((s - 1) & 1 ? hBb : hAb);
    unsigned short* hout = (s & 1) ? hBb : hAb;
    prop_step<false><<<N_NODES / (4 * NPW), 256, 0, stream>>>(hin, h0b, hout,
                                                              rowp, edges);
  }
  prop_step<true><<<N_NODES / (4 * NPW), 256, 0, stream>>>(
      (K_STEPS - 2) & 1 ? hBb : hAb, h0b, outp, rowp, edges);
}

// Round 5
// 658.248 us; speedup vs baseline: 1.3276x; 1.1299x over previous
//
#include <hip/hip_runtime.h>
#include <cstdint>
#include <cstddef>

// ---------------------------------------------------------------------------
// APPNP: h = MLP(x); h0 = h; 10x { h = 0.9 * A_w @ h + 0.1 * h0 }
// MLP in f16 MFMA. Propagation state bf16, accumulate f32.
// R5: CSR build via chunked counting sort — 16 edge-chunks cut same-address
// atomic contention from 16-way to ~1-way, and the atomic's return value is
// the rank, so final scatter is atomic-free. Prop gather loop unrolled 8x.
// ---------------------------------------------------------------------------

#define N_NODES   65536
#define N_EDGES   1048576
#define IN_DIM    500
#define IN_PAD    512
#define HID_DIM   256
#define OUT_DIM   64
#define K_STEPS   10

#define NPW   8      // nodes per wave in prop
#define CAPW  608    // per-wave LDS edge capacity (int2) -> 19456 B/block
#define NCHUNK 16    // counting-sort chunks (chunk = e >> 16)

typedef _Float16 half8 __attribute__((ext_vector_type(8)));
typedef float    f32x4 __attribute__((ext_vector_type(4)));

// ---- workspace layout (bytes) ---------------------------------------------
#define XB_OFF    0ULL                     // 67108864 (f16 x, K-padded)
#define HA_OFF    0ULL                     // bf16 prop ping (8 MB, reuses xb)
#define HB_OFF    33554432ULL              // bf16 prop pong (8 MB)
#define H1_OFF    67108864ULL              // 33554432 (f16)
#define H0_OFF    67108864ULL              // bf16 h0 (8 MB, reuses h1)
#define H2_OFF    100663296ULL             // 33554432 (f16)
// CSR-build scratch lives in the H2 region (free until GEMM2 runs):
#define CNT2_OFF  100663296ULL             // 16*65536*4 = 4194304
#define RANK_OFF  104857600ULL             // E*4 = 4194304
#define TOT_OFF   109051904ULL             // N*4
#define W1T_OFF   134217728ULL             // 262144
#define W2T_OFF   134479872ULL             // 131072
#define W3T_OFF   134610944ULL             // 32768
#define ROWP_OFF  134643712ULL             // (N+1)*4
#define EDG_OFF   135430400ULL             // E*8 (int2: col, w-bits f32)
// end 143819008 (~137 MiB)

__device__ __forceinline__ void gload_lds16(const void* g, void* l) {
  __builtin_amdgcn_global_load_lds(
      (const __attribute__((address_space(1))) void*)g,
      (__attribute__((address_space(3))) void*)l, 16, 0, 0);
}

__device__ __forceinline__ float bf2f(unsigned short u) {
  return __uint_as_float(((unsigned)u) << 16);
}
__device__ __forceinline__ unsigned short f2bf_rne(float f) {
  unsigned u = __float_as_uint(f);
  u += 0x7fffu + ((u >> 16) & 1u);
  return (unsigned short)(u >> 16);
}
__device__ __forceinline__ float uaf(int u) {
  return __uint_as_float((unsigned)u);
}

// ---------------------------------------------------------------------------
// f16 MFMA GEMM. OMODE: 0 = f16 out, 1 = bf16 out (ushort), 2 = f32 out.
// ---------------------------------------------------------------------------
template <int TM, int TN, int WM, int WN, bool RELU, int OMODE>
__global__ __launch_bounds__(256)
void gemm_kernel(const _Float16* __restrict__ A, const _Float16* __restrict__ B,
                 const float* __restrict__ bias, void* __restrict__ Cout,
                 int M, int Nn, int K) {
  static_assert((TM * 8) % 256 == 0 && (TN * 8) % 256 == 0, "tile");
  __shared__ uint4 As[TM * 8];
  __shared__ uint4 Bs[TN * 8];
  const int t    = threadIdx.x;
  const int lane = t & 63;
  const int wave = t >> 6;
  const int wm   = wave / WN;
  const int wn   = wave % WN;
  const int row0 = blockIdx.x * TM;
  const int col0 = blockIdx.y * TN;
  const int l15  = lane & 15;
  const int lq   = lane >> 4;

  f32x4 acc[4][4];
#pragma unroll
  for (int i = 0; i < 4; ++i)
#pragma unroll
    for (int j = 0; j < 4; ++j) acc[i][j] = (f32x4){0.f, 0.f, 0.f, 0.f};

  for (int k0 = 0; k0 < K; k0 += 64) {
#pragma unroll
    for (int i = 0; i < (TM * 8) / 256; ++i) {
      const int c = i * 256 + wave * 64 + lane;
      const int q = c / TM;
      const int r = c % TM;
      gload_lds16(A + (size_t)(row0 + r) * K + (k0 + q * 8),
                  As + i * 256 + wave * 64);
    }
#pragma unroll
    for (int i = 0; i < (TN * 8) / 256; ++i) {
      const int c = i * 256 + wave * 64 + lane;
      const int q = c / TN;
      const int r = c % TN;
      gload_lds16(B + (size_t)(col0 + r) * K + (k0 + q * 8),
                  Bs + i * 256 + wave * 64);
    }
    __syncthreads();
#pragma unroll
    for (int kk = 0; kk < 2; ++kk) {
      const int qa = kk * 4 + lq;
      half8 af[4], bfr[4];
#pragma unroll
      for (int mt = 0; mt < 4; ++mt)
        af[mt] = *((const half8*)(As + (qa * TM + wm * 64 + mt * 16 + l15)));
#pragma unroll
      for (int nt = 0; nt < 4; ++nt)
        bfr[nt] = *((const half8*)(Bs + (qa * TN + wn * 64 + nt * 16 + l15)));
#pragma unroll
      for (int mt = 0; mt < 4; ++mt)
#pragma unroll
        for (int nt = 0; nt < 4; ++nt)
          acc[mt][nt] = __builtin_amdgcn_mfma_f32_16x16x32_f16(
              af[mt], bfr[nt], acc[mt][nt], 0, 0, 0);
    }
    __syncthreads();
  }

#pragma unroll
  for (int mt = 0; mt < 4; ++mt) {
#pragma unroll
    for (int nt = 0; nt < 4; ++nt) {
      const int col = col0 + wn * 64 + nt * 16 + l15;
      const float bv = bias[col];
#pragma unroll
      for (int r = 0; r < 4; ++r) {
        const int row = row0 + wm * 64 + mt * 16 + lq * 4 + r;
        float v = acc[mt][nt][r] + bv;
        if (RELU) v = fmaxf(v, 0.f);
        if (OMODE == 0)
          ((_Float16*)Cout)[(size_t)row * Nn + col] = (_Float16)v;
        else if (OMODE == 1)
          ((unsigned short*)Cout)[(size_t)row * Nn + col] = f2bf_rne(v);
        else
          ((float*)Cout)[(size_t)row * Nn + col] = v;
      }
    }
  }
}

// ---- cast x (fp32 MxK) -> f16 Mx512, zero-padded ---------------------------
__global__ void cast_x_kernel(const float* __restrict__ x,
                              _Float16* __restrict__ xb) {
  const int c = blockIdx.x * blockDim.x + threadIdx.x;
  if (c >= N_NODES * (IN_PAD / 8)) return;
  const int row = c >> 6;
  const int c8  = (c & 63) << 3;
  half8 o;
  if (c8 + 8 <= IN_DIM) {
    const float4* p = (const float4*)(x + (size_t)row * IN_DIM + c8);
    const float4 a = p[0], b = p[1];
    o[0] = (_Float16)a.x; o[1] = (_Float16)a.y;
    o[2] = (_Float16)a.z; o[3] = (_Float16)a.w;
    o[4] = (_Float16)b.x; o[5] = (_Float16)b.y;
    o[6] = (_Float16)b.z; o[7] = (_Float16)b.w;
  } else {
#pragma unroll
    for (int j = 0; j < 8; ++j) {
      const float v = (c8 + j < IN_DIM) ? x[(size_t)row * IN_DIM + c8 + j] : 0.f;
      o[j] = (_Float16)v;
    }
  }
  *(half8*)(xb + (size_t)c * 8) = o;
}

// ---- cast + transpose weight: W[K,N] fp32 -> Wt[N,Kpad] f16 ----------------
__global__ void cast_w_kernel(const float* __restrict__ W,
                              _Float16* __restrict__ Wt, int K, int Kpad,
                              int Nn) {
  const int idx = blockIdx.x * blockDim.x + threadIdx.x;
  if (idx >= Nn * Kpad) return;
  const int n = idx / Kpad;
  const int k = idx % Kpad;
  const float v = (k < K) ? W[(size_t)k * Nn + n] : 0.f;
  Wt[idx] = (_Float16)v;
}

// ---- CSR build: chunked counting sort (low-contention atomics) -------------
// chunk(e) = e >> 16 (16 chunks of 64K edges): avg (chunk,row) count = 1.
__global__ void hist2_kernel(const int* __restrict__ row,
                             int* __restrict__ cnt2, int* __restrict__ rank,
                             int E) {
  const int e = blockIdx.x * blockDim.x + threadIdx.x;
  if (e < E)
    rank[e] = atomicAdd(&cnt2[(e >> 16) * N_NODES + row[e]], 1);
}

__global__ void scan_tot_kernel(const int* __restrict__ cnt2,
                                int* __restrict__ tot) {
  const int r = blockIdx.x * blockDim.x + threadIdx.x;
  int s = 0;
#pragma unroll
  for (int c = 0; c < NCHUNK; ++c) s += cnt2[c * N_NODES + r];
  tot[r] = s;
}

// single-block exclusive scan of tot -> rowptr
__global__ void scan_kernel(const int4* __restrict__ counts4,
                            int* __restrict__ rowptr) {
  __shared__ int part[1024];
  const int t = threadIdx.x;
  const int base = t * 16;  // int4 units; 64 ints per thread
  int4 c[16];
  int s = 0;
#pragma unroll
  for (int i = 0; i < 16; ++i) {
    c[i] = counts4[base + i];
    s += c[i].x + c[i].y + c[i].z + c[i].w;
  }
  part[t] = s;
  __syncthreads();
  for (int off = 1; off < 1024; off <<= 1) {
    const int v = (t >= off) ? part[t - off] : 0;
    __syncthreads();
    part[t] += v;
    __syncthreads();
  }
  int run = (t == 0) ? 0 : part[t - 1];
#pragma unroll
  for (int i = 0; i < 16; ++i) {
    int4 r;
    r.x = run; run += c[i].x;
    r.y = run; run += c[i].y;
    r.z = run; run += c[i].z;
    r.w = run; run += c[i].w;
    ((int4*)rowptr)[base + i] = r;
  }
  if (t == 1023) rowptr[N_NODES] = run;
}

// cnt2[c][r] <- rowptr[r] + prefix_c(cnt2[.][r])   (in place, per-column)
__global__ void chunkbase_kernel(int* __restrict__ cnt2,
                                 const int* __restrict__ rowptr) {
  const int r = blockIdx.x * blockDim.x + threadIdx.x;
  int run = rowptr[r];
#pragma unroll
  for (int c = 0; c < NCHUNK; ++c) {
    const int t = cnt2[c * N_NODES + r];
    cnt2[c * N_NODES + r] = run;
    run += t;
  }
}

// atomic-free scatter: pos = chunkbase + rank
__global__ void scatter2_kernel(const int* __restrict__ row,
                                const int* __restrict__ col,
                                const float* __restrict__ w,
                                const int* __restrict__ rank,
                                const int* __restrict__ cbase,
                                int2* __restrict__ edges, int E) {
  const int e = blockIdx.x * blockDim.x + threadIdx.x;
  if (e < E) {
    const int pos = cbase[(e >> 16) * N_NODES + row[e]] + rank[e];
    edges[pos] = make_int2(col[e], __float_as_int(w[e]));
  }
}

// ---- propagation: wave handles NPW nodes; edges staged in LDS --------------
template <bool OUT_F32>
__global__ __launch_bounds__(256)
void prop_step(const unsigned short* __restrict__ hin,
               const unsigned short* __restrict__ h0,
               void* __restrict__ hout, const int* __restrict__ rowptr,
               const int2* __restrict__ edges) {
  __shared__ int2 eb[4][CAPW];
  const int wave = threadIdx.x >> 6;
  const int lane = threadIdx.x & 63;
  const int node0 = (blockIdx.x * 4 + wave) * NPW;

  const int rp  = rowptr[node0 + min(lane, NPW)];
  const int beg = __shfl(rp, 0);
  const int nE  = __shfl(rp, NPW) - beg;
  const int rrel = rp - beg;
  int2* __restrict__ ebw = eb[wave];

  const bool fast = (nE <= CAPW);
  if (fast) {
    for (int i = lane; i < nE; i += 64) ebw[i] = edges[beg + i];
    __builtin_amdgcn_s_waitcnt(0);  // drain vm+lgkm: staging visible wave-wide
  }

  for (int i = 0; i < NPW; ++i) {
    const int nb = __shfl(rrel, i);
    const int ne = __shfl(rrel, i + 1);
    float a0 = 0.f, a1 = 0.f, a2 = 0.f, a3 = 0.f;
    if (fast) {
      int j = nb;
      for (; j + 8 <= ne; j += 8) {  // 8 gathers in flight per wave
        const int2 e0 = ebw[j + 0];
        const int2 e1 = ebw[j + 1];
        const int2 e2 = ebw[j + 2];
        const int2 e3 = ebw[j + 3];
        const int2 e4 = ebw[j + 4];
        const int2 e5 = ebw[j + 5];
        const int2 e6 = ebw[j + 6];
        const int2 e7 = ebw[j + 7];
        const float v0 = bf2f(hin[((size_t)e0.x << 6) | lane]);
        const float v1 = bf2f(hin[((size_t)e1.x << 6) | lane]);
        const float v2 = bf2f(hin[((size_t)e2.x << 6) | lane]);
        const float v3 = bf2f(hin[((size_t)e3.x << 6) | lane]);
        const float v4 = bf2f(hin[((size_t)e4.x << 6) | lane]);
        const float v5 = bf2f(hin[((size_t)e5.x << 6) | lane]);
        const float v6 = bf2f(hin[((size_t)e6.x << 6) | lane]);
        const float v7 = bf2f(hin[((size_t)e7.x << 6) | lane]);
        a0 = fmaf(uaf(e0.y), v0, a0);
        a1 = fmaf(uaf(e1.y), v1, a1);
        a2 = fmaf(uaf(e2.y), v2, a2);
        a3 = fmaf(uaf(e3.y), v3, a3);
        a0 = fmaf(uaf(e4.y), v4, a0);
        a1 = fmaf(uaf(e5.y), v5, a1);
        a2 = fmaf(uaf(e6.y), v6, a2);
        a3 = fmaf(uaf(e7.y), v7, a3);
      }
      for (; j + 4 <= ne; j += 4) {
        const int2 e0 = ebw[j + 0];
        const int2 e1 = ebw[j + 1];
        const int2 e2 = ebw[j + 2];
        const int2 e3 = ebw[j + 3];
        const float v0 = bf2f(hin[((size_t)e0.x << 6) | lane]);
        const float v1 = bf2f(hin[((size_t)e1.x << 6) | lane]);
        const float v2 = bf2f(hin[((size_t)e2.x << 6) | lane]);
        const float v3 = bf2f(hin[((size_t)e3.x << 6) | lane]);
        a0 = fmaf(uaf(e0.y), v0, a0);
        a1 = fmaf(uaf(e1.y), v1, a1);
        a2 = fmaf(uaf(e2.y), v2, a2);
        a3 = fmaf(uaf(e3.y), v3, a3);
      }
      for (; j < ne; ++j) {
        const int2 e = ebw[j];
        a0 = fmaf(uaf(e.y), bf2f(hin[((size_t)e.x << 6) | lane]), a0);
      }
    } else {  // degenerate degree distribution: direct-global path
      for (int j = nb; j < ne; ++j) {
        const int2 e = edges[beg + j];
        a0 = fmaf(uaf(e.y), bf2f(hin[((size_t)e.x << 6) | lane]), a0);
      }
    }
    const float acc = (a0 + a1) + (a2 + a3);
    const size_t o = ((size_t)(node0 + i) << 6) | lane;
    const float r = 0.9f * acc + 0.1f * bf2f(h0[o]);
    if (OUT_F32)
      ((float*)hout)[o] = r;
    else
      ((unsigned short*)hout)[o] = f2bf_rne(r);
  }
}

// ---------------------------------------------------------------------------
extern "C" void kernel_launch(void* const* d_in, const int* in_sizes, int n_in,
                              void* d_out, int out_size, void* d_ws,
                              size_t ws_size, hipStream_t stream) {
  const float* x  = (const float*)d_in[0];
  const float* W1 = (const float*)d_in[1];
  const float* b1 = (const float*)d_in[2];
  const float* W2 = (const float*)d_in[3];
  const float* b2 = (const float*)d_in[4];
  const float* W3 = (const float*)d_in[5];
  const float* b3 = (const float*)d_in[6];
  const float* ew = (const float*)d_in[7];
  const int* erow = (const int*)d_in[8];
  const int* ecol = (const int*)d_in[9];

  char* ws = (char*)d_ws;
  _Float16* xb  = (_Float16*)(ws + XB_OFF);
  _Float16* h1  = (_Float16*)(ws + H1_OFF);
  _Float16* h2  = (_Float16*)(ws + H2_OFF);
  _Float16* w1t = (_Float16*)(ws + W1T_OFF);
  _Float16* w2t = (_Float16*)(ws + W2T_OFF);
  _Float16* w3t = (_Float16*)(ws + W3T_OFF);
  unsigned short* h0b = (unsigned short*)(ws + H0_OFF);
  unsigned short* hAb = (unsigned short*)(ws + HA_OFF);
  unsigned short* hBb = (unsigned short*)(ws + HB_OFF);
  int* rowp     = (int*)(ws + ROWP_OFF);
  int* cnt2     = (int*)(ws + CNT2_OFF);
  int* rankb    = (int*)(ws + RANK_OFF);
  int* tot      = (int*)(ws + TOT_OFF);
  int2* edges   = (int2*)(ws + EDG_OFF);
  float* outp   = (float*)d_out;

  // --- CSR build (chunked counting sort; scratch in H2 region — free until
  // GEMM2, stream-ordered) ---------------------------------------------------
  hipMemsetAsync(cnt2, 0, NCHUNK * N_NODES * sizeof(int), stream);
  hist2_kernel<<<N_EDGES / 256, 256, 0, stream>>>(erow, cnt2, rankb, N_EDGES);
  scan_tot_kernel<<<N_NODES / 256, 256, 0, stream>>>(cnt2, tot);
  scan_kernel<<<1, 1024, 0, stream>>>((const int4*)tot, rowp);
  chunkbase_kernel<<<N_NODES / 256, 256, 0, stream>>>(cnt2, rowp);
  scatter2_kernel<<<N_EDGES / 256, 256, 0, stream>>>(erow, ecol, ew, rankb,
                                                     cnt2, edges, N_EDGES);

  // --- MLP ------------------------------------------------------------------
  cast_x_kernel<<<(N_NODES * (IN_PAD / 8)) / 256, 256, 0, stream>>>(x, xb);
  cast_w_kernel<<<(HID_DIM * IN_PAD) / 256, 256, 0, stream>>>(W1, w1t, IN_DIM,
                                                              IN_PAD, HID_DIM);
  cast_w_kernel<<<(HID_DIM * HID_DIM) / 256, 256, 0, stream>>>(
      W2, w2t, HID_DIM, HID_DIM, HID_DIM);
  cast_w_kernel<<<(OUT_DIM * HID_DIM) / 256, 256, 0, stream>>>(
      W3, w3t, HID_DIM, HID_DIM, OUT_DIM);

  gemm_kernel<128, 128, 2, 2, true, 0>
      <<<dim3(N_NODES / 128, HID_DIM / 128), 256, 0, stream>>>(
          xb, w1t, b1, h1, N_NODES, HID_DIM, IN_PAD);
  gemm_kernel<128, 128, 2, 2, true, 0>
      <<<dim3(N_NODES / 128, HID_DIM / 128), 256, 0, stream>>>(
          h1, w2t, b2, h2, N_NODES, HID_DIM, HID_DIM);
  gemm_kernel<256, 64, 4, 1, false, 1>
      <<<dim3(N_NODES / 256, 1), 256, 0, stream>>>(h2, w3t, b3, h0b, N_NODES,
                                                   OUT_DIM, HID_DIM);

  // --- K=10 propagation (bf16 state; last step writes f32 to d_out) --------
  for (int s = 0; s < K_STEPS - 1; ++s) {
    const unsigned short* hin = (s == 0) ? h0b : ((s - 1) & 1 ? hBb : hAb);
    unsigned short* hout = (s & 1) ? hBb : hAb;
    prop_step<false><<<N_NODES / (4 * NPW), 256, 0, stream>>>(hin, h0b, hout,
                                                              rowp, edges);
  }
  prop_step<true><<<N_NODES / (4 * NPW), 256, 0, stream>>>(
      (K_STEPS - 2) & 1 ? hBb : hAb, h0b, outp, rowp, edges);
}